// Round 7
// baseline (387.842 us; speedup 1.0000x reference)
//
#include <hip/hip_runtime.h>

// Problem constants (from reference)
#define CC 252
#define NSTEPS 232        // C - SCAN_LEN_OFFSET
#define OUTC 484          // 2*NSTEPS + 20
#define NROWS (128 * 1024)
#define ROWS_PER_BLOCK 256
#define ROW_F4 63         // 252 floats per row = 63 float4

#define INITIAL_DELTA 0.1f
#define DELTA_LOW 0.02f
#define DELTA_HIGH 0.1f

#define STG 11            // stage row stride in float4 (44 floats = 176B):
                          // write banks: (3r+v) mod 8 uniform -> conflict-free
                          // read banks:  (3t+k) mod 8 uniform -> conflict-free
#define BITS_STRIDE 17    // u32 per row (16 words + 1 pad), odd stride

// Scan NV float4 (4*NV steps), packing up/dn bits into uw/dw.
template<int NV>
__device__ __forceinline__ void scan_vecs(const float4* xv, unsigned& uw, unsigned& dw,
                                          float& dc, float& delta, float& tc, float& ntc)
{
    uw = 0u; dw = 0u;
    #pragma unroll
    for (int k = 0; k < NV; ++k) {
        float xs[4] = {xv[k].x, xv[k].y, xv[k].z, xv[k].w};
        #pragma unroll
        for (int j = 0; j < 4; ++j) {
            float xi = xs[j];
            bool up = xi > dc + delta;
            bool dn = xi < dc - delta;
            bool trig = up || dn;
            tc  = trig ? tc + 1.0f : 0.0f;
            ntc = trig ? 0.0f : ntc + 1.0f;
            delta = (tc  >= 3.0f) ? DELTA_LOW  : delta;
            delta = (ntc >= 3.0f) ? DELTA_HIGH : delta;
            dc = trig ? xi : dc;
            uw |= (up ? 1u : 0u) << (k * 4 + j);
            dw |= (dn ? 1u : 0u) << (k * 4 + j);
        }
    }
}

__global__ __launch_bounds__(256) void DeltaModulator_kernel(
    const float* __restrict__ x, float* __restrict__ out)
{
    __shared__ float4   stage[ROWS_PER_BLOCK * STG];             // 45056 B
    __shared__ unsigned bits_lds[ROWS_PER_BLOCK * BITS_STRIDE];  // 17408 B

    const int t = threadIdx.x;
    const int row0 = blockIdx.x * ROWS_PER_BLOCK;
    const int rsub = t >> 3;   // 0..31: which row-slice this thread loads
    const int v    = t & 7;    // 0..7 : which float4 within the 32-col segment

    const float4* __restrict__ xb =
        reinterpret_cast<const float4*>(x) + (size_t)row0 * ROW_F4;

    float dc = 0.0f, delta = INITIAL_DELTA, tc = 0.0f, ntc = 0.0f;
    unsigned* __restrict__ myb = &bits_lds[t * BITS_STRIDE];

    float4 greg[8], rowreg[8];

    // Preload chunk 0: rows (i*32+rsub), vecs v  -- wave reads 8 rows x 128B
    // contiguous segments = all-full-line, minimal request count.
    #pragma unroll
    for (int i = 0; i < 8; ++i)
        greg[i] = xb[(size_t)(i * 32 + rsub) * ROW_F4 + v];

    // 8 chunks: ch 0..6 are 32-step chunks (vecs ch*8..ch*8+7);
    // ch 7 is the tail (vecs 56..62: 8 scan steps + 20 extra floats).
    #pragma unroll
    for (int ch = 0; ch < 8; ++ch) {
        __syncthreads();   // prior chunk's stage reads complete -> safe overwrite
        #pragma unroll
        for (int i = 0; i < 8; ++i)
            stage[(i * 32 + rsub) * STG + v] = greg[i];
        __syncthreads();   // stage ready

        #pragma unroll
        for (int k = 0; k < 8; ++k)
            rowreg[k] = stage[t * STG + k];

        // Prefetch next chunk BEFORE the scan so loads fly under the VALU chain.
        if (ch < 6) {
            #pragma unroll
            for (int i = 0; i < 8; ++i)
                greg[i] = xb[(size_t)(i * 32 + rsub) * ROW_F4 + (ch + 1) * 8 + v];
        } else if (ch == 6) {
            // tail has only 7 vecs (56..62); v==7 keeps stale greg (slot never read)
            if (v < 7) {
                #pragma unroll
                for (int i = 0; i < 8; ++i)
                    greg[i] = xb[(size_t)(i * 32 + rsub) * ROW_F4 + 56 + v];
            }
        }

        unsigned uw, dw;
        if (ch < 7) {
            scan_vecs<8>(rowreg, uw, dw, dc, delta, tc, ntc);
            myb[ch] = uw;  myb[8 + ch] = dw;
        } else {
            // steps 224..231 from tail vecs 56,57
            scan_vecs<2>(rowreg, uw, dw, dc, delta, tc, ntc);
            myb[7] = uw;   myb[15] = dw;
        }
    }

    __syncthreads();   // bits ready; tail chunk stays resident in stage (extra)

    // ============ Phase B: wave-coalesced expansion of 256 rows ============
    // Thread t handles region-flat float4 index G = i*256 + t, i = 0..120.
    float4* __restrict__ o4 = reinterpret_cast<float4*>(out + (size_t)row0 * OUTC);

    int r = (t >= 242) ? 2 : ((t >= 121) ? 1 : 0);
    int f = t - r * 121;

    #pragma unroll 1
    for (int i = 0; i < 121; ++i) {
        float4 w;
        if (f < 116) {
            const int idx   = (f < 58) ? f : f - 58;
            const int wbase = (f < 58) ? 0 : 8;
            const unsigned word = bits_lds[r * BITS_STRIDE + wbase + (idx >> 3)];
            const int s = 4 * (idx & 7);
            w = make_float4((float)((word >> s) & 1u),
                            (float)((word >> (s + 1)) & 1u),
                            (float)((word >> (s + 2)) & 1u),
                            (float)((word >> (s + 3)) & 1u));
        } else {
            // extra floats: tail vec (58 + (f-116)) lives at stage slot 2+(f-116)
            w = stage[r * STG + 2 + (f - 116)];
        }
        o4[r * 121 + f] = w;

        // advance G by 256: 256 = 2*121 + 14
        f += 14; r += 2;
        if (f >= 121) { f -= 121; r += 1; }
    }
}

extern "C" void kernel_launch(void* const* d_in, const int* in_sizes, int n_in,
                              void* d_out, int out_size, void* d_ws, size_t ws_size,
                              hipStream_t stream) {
    const float* x = (const float*)d_in[0];
    float* out = (float*)d_out;
    const int threads = 256;
    const int blocks = NROWS / ROWS_PER_BLOCK; // 512
    DeltaModulator_kernel<<<blocks, threads, 0, stream>>>(x, out);
}